// Round 9
// baseline (622.228 us; speedup 1.0000x reference)
//
#include <hip/hip_runtime.h>

typedef __attribute__((ext_vector_type(8))) short short8;
typedef __attribute__((ext_vector_type(4))) float f32x4;
typedef __attribute__((ext_vector_type(4))) unsigned short us4;

#define LEAK 0.2f

__device__ __forceinline__ float b2f(unsigned short s) {
    unsigned u = ((unsigned)s) << 16;
    return __builtin_bit_cast(float, u);
}
__device__ __forceinline__ unsigned short f2b(float f) {
    unsigned u = __builtin_bit_cast(unsigned, f);
    u += 0x7fffu + ((u >> 16) & 1u);
    return (unsigned short)(u >> 16);
}

// async 16B global->LDS (direct-to-shared DMA). LDS base wave-uniform; HW adds lane*16.
__device__ __forceinline__ void async16(const short* g, short* l) {
    __builtin_amdgcn_global_load_lds(
        (const __attribute__((address_space(1))) void*)g,
        (__attribute__((address_space(3))) void*)l, 16, 0, 0);
}

// ---------------- prep: upsample / warp / cost volume (LDS-staged, coalesced) ----
// Block = 64 pixels of one row (quarter row). All global I/O is 16B/lane contiguous.
// vol: halo layout [B,130,258,144] bf16; interior pixel (h,w) -> row h+1, col w+1.
// ch 0..127 = left(bf16), 128..132 = costs, 133 = up, 134..143 = 0.
__global__ __launch_bounds__(256)
void prep_kernel(const float* __restrict__ left, const float* __restrict__ right,
                 const float* __restrict__ pd, short* __restrict__ vol) {
    __shared__ __align__(16) float inL[64 * 132];   // [px][128 ch + 4 pad]
    __shared__ __align__(16) float rrow[256];       // right row (b,h)
    __shared__ __align__(16) float pr0[128];        // pd row y0c
    __shared__ __align__(16) float pr1[128];        // pd row y1c
    __shared__ __align__(16) short outT[64 * 144];  // output tile

    int t = threadIdx.x;
    int blk = blockIdx.x;                 // 4096 = b(8) * h(128) * wq(4)
    int wq = blk & 3, h = (blk >> 2) & 127, b = blk >> 9;
    int w0 = wq << 6;

    // row-uniform upsample y terms
    float sy = h * 0.5f - 0.25f;
    float fy0 = floorf(sy);
    float fy = sy - fy0;
    int y0 = (int)fy0;
    int y0c = min(max(y0, 0), 63), y1c = min(max(y0 + 1, 0), 63);

    // ---- phase 1: coalesced loads -> LDS ----
    const float* lp = left + ((size_t)((b * 128 + h) * 256 + w0)) * 128;
#pragma unroll
    for (int k2 = 0; k2 < 8; ++k2) {
        int g = t + k2 * 256;             // granule 0..2047 (16B each)
        int p = g >> 5, j = g & 31;
        float4 v = *(const float4*)(lp + (size_t)g * 4);
        *(float4*)(&inL[p * 132 + j * 4]) = v;
    }
    if (t < 64) {
        *(float4*)(&rrow[t * 4]) =
            *(const float4*)(right + ((size_t)(b * 128 + h)) * 256 + t * 4);
    } else if (t < 96) {
        int i2 = t - 64;
        *(float4*)(&pr0[i2 * 4]) = *(const float4*)(pd + (size_t)(b * 64 + y0c) * 128 + i2 * 4);
    } else if (t < 128) {
        int i2 = t - 96;
        *(float4*)(&pr1[i2 * 4]) = *(const float4*)(pd + (size_t)(b * 64 + y1c) * 128 + i2 * 4);
    }
    __syncthreads();

    // ---- phase 2: 4 threads per pixel ----
    int p = t >> 2, s = t & 3;
    int w = w0 + p;
    const float* src = &inL[p * 132 + s * 32];
    short* odst = &outT[p * 144 + s * 32];
    float sum = 0.f;
#pragma unroll
    for (int i = 0; i < 8; ++i) {
        float f0 = src[i * 4], f1 = src[i * 4 + 1], f2 = src[i * 4 + 2], f3 = src[i * 4 + 3];
        sum += (f0 + f1) + (f2 + f3);
        us4 o;
        o.x = f2b(f0); o.y = f2b(f1); o.z = f2b(f2); o.w = f2b(f3);
        *(us4*)(odst + i * 4) = o;
    }
    sum += __shfl_xor(sum, 1);
    sum += __shfl_xor(sum, 2);
    float mean = sum * (1.f / 128.f);

    float one_fy = 1.f - fy;
#pragma unroll
    for (int tap = s; tap < 5; tap += 4) {   // s=0 -> taps 0,4; s=1,2,3 -> taps 1,2,3
        int jj = w + tap - 2;
        if (jj >= 0 && jj < 256) {
            float sx = jj * 0.5f - 0.25f;
            float fx0 = floorf(sx);
            float fx = sx - fx0;
            int x0 = (int)fx0;
            int x0c = min(max(x0, 0), 127), x1c = min(max(x0 + 1, 0), 127);
            float up = one_fy * ((1.f - fx) * pr0[x0c] + fx * pr0[x1c])
                     + fy     * ((1.f - fx) * pr1[x0c] + fx * pr1[x1c]);
            float cx = (float)jj - up;
            float xf0 = floorf(cx), xf1 = xf0 + 1.f;
            float w0x = xf1 - cx, w1x = cx - xf0;
            int ix0 = (int)fminf(fmaxf(xf0, 0.f), 255.f);
            int ix1 = (int)fminf(fmaxf(xf1, 0.f), 255.f);
            float warped = w0x * rrow[ix0] + w1x * rrow[ix1];
            outT[p * 144 + 128 + tap] = (short)f2b(warped * mean);
            if (tap == 2) outT[p * 144 + 133] = (short)f2b(up);   // jj==w always in-range
        } else {
            outT[p * 144 + 128 + tap] = 0;
        }
    }
    if (s == 0) { outT[p * 144 + 134] = 0; outT[p * 144 + 135] = 0; }
    if (s == 3) {
        us4 z = {};
        *(us4*)(&outT[p * 144 + 136]) = z;
        *(us4*)(&outT[p * 144 + 140]) = z;
    }
    __syncthreads();

    // ---- phase 3: coalesced store (tile is contiguous in halo layout) ----
    short* gdst = vol + ((size_t)(b * 130 + h + 1) * 258 + (w0 + 1)) * 144;
    for (int g = t; g < 1152; g += 256)
        *(short8*)(gdst + g * 8) = *(const short8*)(&outT[g * 8]);
}

// zero the halo ring of ONE buffer (schedule AFTER last reader of aliased layout)
__global__ void halo_zero_one(short* __restrict__ buf, int C) {
    int nchunk = C >> 3;
    int slot = blockIdx.x * 256 + threadIdx.x;
    int total = 8 * 772 * nchunk;
    if (slot >= total) return;
    int chunk = slot % nchunk;
    int pix = slot / nchunk;
    int b = pix / 772, p = pix % 772;
    int row, col;
    if (p < 516) { row = (p < 258) ? 0 : 129; col = (p < 258) ? p : p - 258; }
    else { int q = p - 516; row = 1 + (q >> 1); col = (q & 1) ? 257 : 0; }
    short8 z = {};
    *(short8*)(buf + ((size_t)(b * 130 + row) * 258 + col) * C + chunk * 8) = z;
}

// fp32 HWIO weights -> bf16 swizzled layout, all 5 layers in one launch.
// Layout (shorts): granule g = ((kc*9+tap)*COUT + n)*4 + s, where slot s holds
// k-quarter q = (s - (n>>1)) & 3; within granule, 8 consecutive k (q*8..q*8+7).
// k zero-padded past CIN. Staged to LDS as identity copy (legal for
// global_load_lds); read with slot=(q+(n>>1))&3.
// WHY >>1: LDS serves a wave64 ds_read_b128 in quarter-wave phases of 16 lanes
// with q CONSTANT inside a phase; granule%8 = 4*(n&1) + slot must walk all 8
// bank groups as col=n&15 varies. slot=(q+(n>>1))&3 does; slot=(q+n)&3 and
// plain consecutive-granule layouts do NOT (r0/r7: 8.85M conflict cycles;
// r4/r5/r8 with >>1: exactly 0).
__global__ void wconv_all(const float* __restrict__ k1, const float* __restrict__ k2,
                          const float* __restrict__ k3, const float* __restrict__ k4,
                          const float* __restrict__ k5,
                          short* __restrict__ w1, short* __restrict__ w2,
                          short* __restrict__ w3, short* __restrict__ w4,
                          short* __restrict__ w5) {
    const int CINt[5]  = {134, 128, 128, 96, 64};
    const int COUTt[5] = {128, 128, 96, 64, 32};
    const int KCt[5]   = {5, 4, 4, 3, 2};
    const float* srcs[5] = {k1, k2, k3, k4, k5};
    short* dsts[5] = {w1, w2, w3, w4, w5};
    int l = blockIdx.y;
    int CIN = CINt[l], COUT = COUTt[l], KC = KCt[l];
    const float* k = srcs[l];
    short* wt = dsts[l];
    int idx = blockIdx.x * 256 + threadIdx.x;
    int total = 9 * KC * COUT * 32;
    if (idx >= total) return;
    int j = idx & 7;
    int s = (idx >> 3) & 3;
    int rest = idx >> 5;              // (kc*9+tap)*COUT + n
    int n = rest % COUT; rest /= COUT;
    int tap = rest % 9, kc = rest / 9;
    int q = (s - (n >> 1)) & 3;
    int kk = q * 8 + j;
    int ci = kc * 32 + kk;
    float v = (ci < CIN) ? k[(size_t)(tap * CIN + ci) * COUT + n] : 0.f;
    wt[idx] = (short)f2b(v);
}

// 3x3 SAME conv, halo layout [B,130,258,CIN_STR] -> [B,130,258,COUT].
// Base = round 8 (113us/dispatch, 0 conflicts, no spill, VALU hoisted).
// r8 diagnosis: LDS-read pipe (~10k cy/kc CU-wide) and MFMA pipe (~11.2k
// cy/kc/SIMD) run SERIALLY -- source orders each tap "12 loads, wait, 32
// MFMAs" and at 48-reg peak liveness with 4 spare regs the compiler cannot
// hoist across the MFMA burst (MfmaUtil 35% = 11.2/27k).
// CHANGE (only the inner loop): explicit ring software-pipeline with LOWER
// liveness. W frags flow through bf[3] (12 regs, loaded 2 nt-slots ahead);
// A frags double-buffer areg[2][4] (32 regs) with next tap's 4 reads issued
// in the last two nt-slots of the current tap. Every MFMA quad waits on a
// load issued ~8 MFMAs (~160cy) earlier. Peak operand regs 48 -> 44.
// All indices static (unrolled) -- no scratch.
template <int KC, int CIN_STR, int COUT, int NT, int LASTC>
__launch_bounds__(512, 2)
__global__ void conv3x3_kernel(const short* __restrict__ in, const short* __restrict__ wt,
                               const float* __restrict__ bias, short* __restrict__ out) {
    __shared__ short ldsA[2][10 * 66 * 4 * 8];   // 2 x 42,240 B
    __shared__ short ldsW[9 * COUT * 32];        // COUT=128: 73,728 B
    const int AG = 10 * 66 * 4;                  // 2640 A granules
    const int WSLOTS = 9 * COUT * 4;             // 16B granules in the W slice
    const int WSTRIDE = 9 * COUT * 32;           // shorts per kc slice

    int t = threadIdx.x;
    int lane = t & 63, wid = t >> 6;
    int q = lane >> 4, col = lane & 15;

    int wtile = blockIdx.x & 3;
    int rest = blockIdx.x >> 2;
    int htile = rest & 15, b = rest >> 4;
    int w0h = wtile << 6;                        // staged cols w0h .. w0h+65
    int row0 = htile << 3;                       // staged rows row0 .. row0+9

    const short* inbase = in + ((size_t)(b * 130 + row0) * 258 + w0h) * CIN_STR;

    // ---- hoisted A-stage decomposition (once) ----
    // granule i = rr*264 + p*4 + s; slot s holds channel-chunk c=(s-(p>>1))&3
    int agoff[6];
    unsigned maskAll = 0, maskLast = 0;
#pragma unroll
    for (int sl = 0; sl < 6; ++sl) {
        int i = t + sl * 512;
        int rr = i / 264, rem = i % 264;
        int p = rem >> 2, s = rem & 3;
        int c = (s - (p >> 1)) & 3;
        agoff[sl] = (rr * 258 + p) * CIN_STR + c * 8;
        if (i < AG) {
            maskAll |= 1u << sl;
            if (LASTC == 4 || c < LASTC) maskLast |= 1u << sl;
        }
    }
    int ldst0 = (t & ~63) * 8;                   // shorts; slot sl adds sl*4096

    auto stageA = [&](int kc, int d) {
        short* dst = &ldsA[d][ldst0];
        unsigned m = (kc == KC - 1) ? maskLast : maskAll;
#pragma unroll
        for (int sl = 0; sl < 6; ++sl) {
            if ((m >> sl) & 1)
                async16(inbase + agoff[sl] + kc * 32, dst + sl * 4096);
        }
    };
    auto stageW = [&](int kc) {
        const short* wsrc = wt + (size_t)kc * WSTRIDE;
        short* dst = ldsW + ldst0;
#pragma unroll
        for (int sl = 0; sl < (WSLOTS + 511) / 512; ++sl) {
            int i = t + sl * 512;
            if (i < WSLOTS) async16(wsrc + (size_t)i * 8, dst + sl * 4096);
        }
    };

    // ---- hoisted affine read bases (byte offsets; zero-conflict layout) ----
    int abase[3];
#pragma unroll
    for (int dx = 0; dx < 3; ++dx) {
        int pc = col + dx;
        abase[dx] = (wid * 264 + 4 * pc + ((q + (pc >> 1)) & 3)) * 16;
    }
    int wbase = (4 * col + ((q + (col >> 1)) & 3)) * 16;

    f32x4 acc[4][NT] = {};

    stageW(0);
    stageA(0, 0);
    __syncthreads();

    const char* ldsWb = (const char*)ldsW + wbase;

    for (int kc = 0; kc < KC; ++kc) {
        // prefetch next A chunk; it has the whole compute phase to land
        if (kc + 1 < KC) stageA(kc + 1, (kc + 1) & 1);
        const char* Ab = (const char*)&ldsA[kc & 1][0];

        short8 areg[2][4], bf[3];
        // preload tap 0 A fragments
#pragma unroll
        for (int mt = 0; mt < 4; ++mt)
            areg[0][mt] = *(const short8*)(Ab + abase[0] + mt * 1024);

#pragma unroll
        for (int ti = 0; ti < 9; ++ti) {
            const int dyn = (ti + 1) / 3, dxn = (ti + 1) % 3;   // next tap coords
            const char* wp = ldsWb + (size_t)ti * (COUT * 64);
            bf[0] = *(const short8*)(wp);
            if (NT > 1) bf[1] = *(const short8*)(wp + 1024);
#pragma unroll
            for (int nt = 0; nt < NT; ++nt) {
                if (nt + 2 < NT) {
                    // W ring: load the frag used 2 iterations from now
                    bf[(nt + 2) % 3] = *(const short8*)(wp + (nt + 2) * 1024);
                } else if (ti < 8) {
                    // last two slots: prefetch next tap's A (2 frags each)
                    const char* an = Ab + dyn * 4224 + abase[dxn];
                    if (nt + 2 == NT) {
                        areg[(ti + 1) & 1][0] = *(const short8*)(an);
                        areg[(ti + 1) & 1][1] = *(const short8*)(an + 1024);
                    } else {
                        areg[(ti + 1) & 1][2] = *(const short8*)(an + 2048);
                        areg[(ti + 1) & 1][3] = *(const short8*)(an + 3072);
                    }
                }
#pragma unroll
                for (int mt = 0; mt < 4; ++mt)
                    acc[mt][nt] = __builtin_amdgcn_mfma_f32_16x16x32_bf16(
                        areg[ti & 1][mt], bf[nt % 3], acc[mt][nt], 0, 0, 0);
            }
        }
        __syncthreads();                 // drains A(kc+1) prefetch: free by now
        if (kc + 1 < KC) {
            stageW(kc + 1);              // L2-resident, ~1k cy exposed
            __syncthreads();
        }
    }

    // ---- epilogue: D[m = mt*16 + q*4 + rr][n = nt*16 + col], leaky-relu, bf16 ----
    size_t obase = ((size_t)(b * 130 + row0 + 1 + wid) * 258 + (w0h + 1)) * COUT;
#pragma unroll
    for (int nt = 0; nt < NT; ++nt) {
        int n = nt * 16 + col;
        float bv = bias[n];
#pragma unroll
        for (int mt = 0; mt < 4; ++mt) {
#pragma unroll
            for (int rr = 0; rr < 4; ++rr) {
                int m = mt * 16 + q * 4 + rr;
                float v = acc[mt][nt][rr] + bv;
                v = (v >= 0.f) ? v : LEAK * v;
                out[obase + (size_t)m * COUT + n] = (short)f2b(v);
            }
        }
    }
}

// conv6: 3x3, Cin=32 (halo layout), Cout=1, linear, fp32 out (flat [B,H,W])
__global__ void conv6_kernel(const short* __restrict__ x, const float* __restrict__ k,
                             const float* __restrict__ bias, float* __restrict__ out) {
    __shared__ float wk[288];
    int t = threadIdx.x;
    for (int i = t; i < 288; i += 256) wk[i] = k[i];
    __syncthreads();
    int idx = blockIdx.x * 256 + t;
    int w = idx & 255, h = (idx >> 8) & 127, b = idx >> 15;
    float acc = bias[0];
#pragma unroll
    for (int dy = 0; dy < 3; ++dy) {
#pragma unroll
        for (int dx = 0; dx < 3; ++dx) {
            const short* xp = x + ((size_t)(b * 130 + h + dy) * 258 + (w + dx)) * 32;
            const float* wp = wk + (dy * 3 + dx) * 32;
#pragma unroll
            for (int c8 = 0; c8 < 4; ++c8) {
                short8 v = *(const short8*)(xp + c8 * 8);
#pragma unroll
                for (int j = 0; j < 8; ++j)
                    acc += b2f((unsigned short)v[j]) * wp[c8 * 8 + j];
            }
        }
    }
    out[idx] = acc;
}

extern "C" void kernel_launch(void* const* d_in, const int* in_sizes, int n_in,
                              void* d_out, int out_size, void* d_ws, size_t ws_size,
                              hipStream_t stream) {
    const float* left  = (const float*)d_in[0];
    const float* right = (const float*)d_in[1];
    const float* pd    = (const float*)d_in[2];
    const float* k[6];
    const float* bb[6];
    for (int i = 0; i < 6; ++i) { k[i] = (const float*)d_in[3 + 2 * i]; bb[i] = (const float*)d_in[4 + 2 * i]; }

    char* ws = (char*)d_ws;
    // weights: [0, 1 MiB)
    short* wt1 = (short*)ws;
    short* wt2 = (short*)(ws + 368640);
    short* wt3 = (short*)(ws + 663552);
    short* wt4 = (short*)(ws + 884736);
    short* wt5 = (short*)(ws + 995328);
    // region A @1 MiB: vol(C=144) -> X2(128) -> X4(64); region B: X1(128) -> X3(96) -> X5(32)
    short* vol = (short*)(ws + 1048576);
    short* X1  = (short*)(ws + 1048576 + 77276160);
    short* X2  = vol;
    short* X3  = X1;
    short* X4  = vol;
    short* X5  = X1;

    auto hz = [&](short* buf, int C) {
        int blocks = (8 * 772 * (C >> 3) + 255) / 256;
        halo_zero_one<<<blocks, 256, 0, stream>>>(buf, C);
    };

    prep_kernel<<<4096, 256, 0, stream>>>(left, right, pd, vol);
    wconv_all<<<dim3(720, 5), 256, 0, stream>>>(k[0], k[1], k[2], k[3], k[4],
                                                wt1, wt2, wt3, wt4, wt5);
    hz(vol, 144);
    hz(X1, 128);

    conv3x3_kernel<5, 144, 128, 8, 2><<<512, 512, 0, stream>>>(vol, wt1, bb[0], X1);
    hz(X2, 128);   // region A: only after conv1 finished reading vol
    conv3x3_kernel<4, 128, 128, 8, 4><<<512, 512, 0, stream>>>(X1, wt2, bb[1], X2);
    hz(X3, 96);    // region B: only after conv2 finished reading X1
    conv3x3_kernel<4, 128,  96, 6, 4><<<512, 512, 0, stream>>>(X2, wt3, bb[2], X3);
    hz(X4, 64);    // region A: only after conv3 finished reading X2
    conv3x3_kernel<3,  96,  64, 4, 4><<<512, 512, 0, stream>>>(X3, wt4, bb[3], X4);
    hz(X5, 32);    // region B: only after conv4 finished reading X3
    conv3x3_kernel<2,  64,  32, 2, 4><<<512, 512, 0, stream>>>(X4, wt5, bb[4], X5);
    conv6_kernel<<<1024, 256, 0, stream>>>(X5, k[5], bb[5], (float*)d_out);
}